// Round 8
// baseline (158.983 us; speedup 1.0000x reference)
//
#include <hip/hip_runtime.h>

#define T_LEN 3000
#define DM 1280
#define NUM_HEADS 20
#define N_CH 4
#define CHUNK 750
#define CHUNK_PAD 768
#define T_PAD 3072

typedef __bf16 bf16x8 __attribute__((ext_vector_type(8)));
typedef float f32x4 __attribute__((ext_vector_type(4)));

typedef const __attribute__((address_space(1))) void* gas_p;
typedef __attribute__((address_space(3))) void* las_p;
#define GLOAD16(g, l) __builtin_amdgcn_global_load_lds((gas_p)(g), (las_p)(l), 16, 0, 0)

__device__ __forceinline__ unsigned short f2bf(float f) {
  union { float f; unsigned u; } x; x.f = f;
  unsigned r = x.u + 0x7FFFu + ((x.u >> 16) & 1u);
  return (unsigned short)(r >> 16);
}

// ---------------- fp32 -> bf16 with zero-fill of pad rows ----------------
__global__ __launch_bounds__(256) void cvt_bf16_kernel(
    const float* __restrict__ in, unsigned short* __restrict__ out) {
  int i = blockIdx.x * 256 + threadIdx.x;
  ushort4 o;
  if (i < T_LEN * DM / 4) {
    const float4 v = ((const float4*)in)[i];
    o.x = f2bf(v.x); o.y = f2bf(v.y); o.z = f2bf(v.z); o.w = f2bf(v.w);
  } else {
    o.x = 0; o.y = 0; o.z = 0; o.w = 0;
  }
  ((ushort4*)out)[i] = o;
}

// ------- transpose 4x 1280x1280 fp32 -> bf16 concat: out[z][n][k] = w[z][k][n]
__global__ __launch_bounds__(256) void tr_bf16_kernel(
    const float* __restrict__ w0, const float* __restrict__ w1,
    const float* __restrict__ w2, const float* __restrict__ w3,
    unsigned short* __restrict__ out) {
  const int z = blockIdx.z;
  const float* in = z == 0 ? w0 : (z == 1 ? w1 : (z == 2 ? w2 : w3));
  unsigned short* o = out + (size_t)z * DM * DM;
  __shared__ float tile[32][33];
  const int x = threadIdx.x, y0 = threadIdx.y;
  const int n0 = blockIdx.x * 32, k0 = blockIdx.y * 32;
  for (int y = y0; y < 32; y += 8) tile[y][x] = in[(k0 + y) * DM + n0 + x];
  __syncthreads();
  for (int y = y0; y < 32; y += 8) o[(n0 + y) * DM + k0 + x] = f2bf(tile[x][y]);
}

// ---------------- zero V chunk-pad columns (NaN guard for P=0 * V) ----------
__global__ __launch_bounds__(256) void vpad_zero_kernel(unsigned short* __restrict__ Vtb) {
  int i = blockIdx.x * 256 + threadIdx.x;
  if (i >= NUM_HEADS * 64 * N_CH * (CHUNK_PAD - CHUNK)) return;
  int c = i % (CHUNK_PAD - CHUNK); int r = i / (CHUNK_PAD - CHUNK);
  int ch = r % N_CH; int row = r / N_CH;
  Vtb[(size_t)row * T_PAD + ch * CHUNK_PAD + CHUNK + c] = 0;
}

// ---------------- fused QKV GEMM: 256x256 tile, 8-phase pipeline ------------
// BM=BN=256, BK=64, 512 thr (8 waves 2Mx4N), dbuf LDS 128 KiB.
// Per iter: 2 K-tiles, 8 phases; each phase = {12 ds_read_b128; stage 1
// half-tile; barrier; setprio(1); 16 MFMA; setprio(0); [vmcnt gate]; barrier}.
// Stage schedule (1 half/phase, each >=1 barrier after its last reader):
//   ph1: b1.Ah1(t1)  ph2: b1.Bh1(t1)  ph3: b0.Ah0(t0+2) ph4: b0.Bh0(t0+2)
//   ph5: b0.Ah1(t0+2) ph6: b0.Bh1(t0+2) ph7: b1.Ah0(t1+2) ph8: b1.Bh0(t1+2)
// Gates: vmcnt(4) at ph4/ph8 (2 half-tiles in flight; never 0 in steady state).
// Swizzle: LDS[R][c] = src[R][c ^ (R&7)] (pre-swizzled global source, XOR read).
// grid (12, 15); sec = by/5: 0->Q (scaled 1/8), 1->K, 2->V^T
__global__ __launch_bounds__(512, 2) void gemm256_kernel(
    const unsigned short* __restrict__ A, const unsigned short* __restrict__ Bt,
    const float* __restrict__ b0, const float* __restrict__ b1, const float* __restrict__ b2,
    unsigned short* __restrict__ dq, unsigned short* __restrict__ dk,
    unsigned short* __restrict__ dv) {
  __shared__ unsigned short Asd[2][256][64];
  __shared__ unsigned short Bsd[2][256][64];
  const int tid = threadIdx.x;
  const int lane = tid & 63, wave = tid >> 6;       // 8 waves
  const int h = lane >> 4, lr = lane & 15;
  const int wm = wave >> 2, wn = wave & 3;          // 2(M) x 4(N)
  const int t0 = blockIdx.x * 256, n0 = blockIdx.y * 256;

  // staging: per (wave, j-round) 8 rows x 128B; lane covers row r8=lane>>3,
  // 16B chunk lane&7 from source chunk (lane&7)^(r8) (inverse swizzle)
  const int r8 = lane >> 3;
  const int sg = (lane & 7) ^ r8;
  const unsigned short* Ast = A + (size_t)(t0 + wave * 8 + r8) * DM + sg * 8;
  const unsigned short* Bst = Bt + (size_t)(n0 + wave * 8 + r8) * DM + sg * 8;

#define STG_A(BUF, HALF, KT) do {                                                        \
    GLOAD16(Ast + (size_t)((HALF) * 128) * DM + (size_t)(KT) * 64,                       \
            &Asd[BUF][(HALF) * 128 + wave * 8][0]);                                      \
    GLOAD16(Ast + (size_t)((HALF) * 128 + 64) * DM + (size_t)(KT) * 64,                  \
            &Asd[BUF][(HALF) * 128 + 64 + wave * 8][0]);                                 \
  } while (0)
#define STG_B(BUF, HALF, KT) do {                                                        \
    GLOAD16(Bst + (size_t)((HALF) * 128) * DM + (size_t)(KT) * 64,                       \
            &Bsd[BUF][(HALF) * 128 + wave * 8][0]);                                      \
    GLOAD16(Bst + (size_t)((HALF) * 128 + 64) * DM + (size_t)(KT) * 64,                  \
            &Bsd[BUF][(HALF) * 128 + 64 + wave * 8][0]);                                 \
  } while (0)

  f32x4 acc[8][4];
  const f32x4 zero4 = {0.f, 0.f, 0.f, 0.f};
#pragma unroll
  for (int i = 0; i < 8; i++)
#pragma unroll
    for (int j = 0; j < 4; j++) acc[i][j] = zero4;

#define PHASE(BUF, MH, NH, STAGE_STMT, GATE_STMT) do {                                   \
    bf16x8 pa[4][2], pb[2][2];                                                           \
    _Pragma("unroll") for (int mf = 0; mf < 4; mf++)                                     \
      _Pragma("unroll") for (int kk = 0; kk < 2; kk++) {                                 \
        const int R = (MH) * 128 + wm * 64 + mf * 16 + lr;                               \
        pa[mf][kk] = *(const bf16x8*)&Asd[BUF][R][((kk * 4 + h) ^ (lr & 7)) * 8];        \
      }                                                                                  \
    _Pragma("unroll") for (int nf = 0; nf < 2; nf++)                                     \
      _Pragma("unroll") for (int kk = 0; kk < 2; kk++) {                                 \
        const int Cc = (NH) * 128 + wn * 32 + nf * 16 + lr;                              \
        pb[nf][kk] = *(const bf16x8*)&Bsd[BUF][Cc][((kk * 4 + h) ^ (lr & 7)) * 8];       \
      }                                                                                  \
    STAGE_STMT;                                                                          \
    __builtin_amdgcn_s_barrier();                                                        \
    __builtin_amdgcn_s_setprio(1);                                                       \
    _Pragma("unroll") for (int mf = 0; mf < 4; mf++)                                     \
      _Pragma("unroll") for (int nf = 0; nf < 2; nf++)                                   \
        _Pragma("unroll") for (int kk = 0; kk < 2; kk++)                                 \
          acc[(MH) * 4 + mf][(NH) * 2 + nf] = __builtin_amdgcn_mfma_f32_16x16x32_bf16(   \
              pa[mf][kk], pb[nf][kk], acc[(MH) * 4 + mf][(NH) * 2 + nf], 0, 0, 0);       \
    __builtin_amdgcn_s_setprio(0);                                                       \
    GATE_STMT;                                                                           \
    __builtin_amdgcn_s_barrier();                                                        \
  } while (0)

  // prologue: buf0 <- tile0 full; buf1 <- tile1 {Ah0, Bh0}; wait buf0.
  STG_A(0, 0, 0); STG_B(0, 0, 0); STG_A(0, 1, 0); STG_B(0, 1, 0);
  STG_A(1, 0, 1); STG_B(1, 0, 1);
  asm volatile("s_waitcnt vmcnt(4)" ::: "memory");
  __builtin_amdgcn_s_barrier();

#pragma unroll 1
  for (int i = 0; i < 10; ++i) {
    const int tA = 2 * i, tB = 2 * i + 1;
    PHASE(0, 0, 0, STG_A(1, 1, tB), );
    PHASE(0, 0, 1, STG_B(1, 1, tB), );
    PHASE(0, 1, 0, if (i < 9) STG_A(0, 0, tA + 2), );
    PHASE(0, 1, 1, if (i < 9) STG_B(0, 0, tA + 2),
          if (i < 9) { asm volatile("s_waitcnt vmcnt(4)" ::: "memory"); }
          else       { asm volatile("s_waitcnt vmcnt(0)" ::: "memory"); });
    PHASE(1, 0, 0, if (i < 9) STG_A(0, 1, tA + 2), );
    PHASE(1, 0, 1, if (i < 9) STG_B(0, 1, tA + 2), );
    PHASE(1, 1, 0, if (i < 9) STG_A(1, 0, tB + 2), );
    PHASE(1, 1, 1, if (i < 9) STG_B(1, 0, tB + 2),
          if (i < 9) { asm volatile("s_waitcnt vmcnt(4)" ::: "memory"); });
  }
#undef PHASE
#undef STG_A
#undef STG_B

  const int sec = (int)blockIdx.y / 5;
  const float* bias = sec == 0 ? b0 : (sec == 1 ? b1 : b2);
  const float qs = sec == 0 ? 0.125f : 1.0f;
#pragma unroll
  for (int mh = 0; mh < 2; mh++) {
#pragma unroll
    for (int mf = 0; mf < 4; mf++) {
#pragma unroll
      for (int jj = 0; jj < 4; jj++) {
        int t = t0 + mh * 128 + wm * 64 + mf * 16 + h * 4 + jj;
        if (t >= T_LEN) continue;
#pragma unroll
        for (int nh = 0; nh < 2; nh++) {
#pragma unroll
          for (int nf = 0; nf < 2; nf++) {
            int n = n0 + nh * 128 + wn * 32 + nf * 16 + lr;
            int nn = n - sec * DM;
            float v = (acc[mh * 4 + mf][nh * 2 + nf][jj] + bias[nn]) * qs;
            if (sec < 2) {
              unsigned short* dst = sec == 0 ? dq : dk;
              dst[(size_t)(nn >> 6) * (T_PAD * 64) + (size_t)t * 64 + (nn & 63)] = f2bf(v);
            } else {
              int ch = t / CHUNK, s = t - ch * CHUNK;
              dv[(size_t)(nn >> 6) * (64 * T_PAD) + (size_t)(nn & 63) * T_PAD + ch * CHUNK_PAD + s] = f2bf(v);
            }
          }
        }
      }
    }
  }
}

// ---------------- out-proj GEMM: R7 128x64 m97 structure (unchanged) --------
__global__ __launch_bounds__(256) void gemm_out_kernel(
    const unsigned short* __restrict__ A, const unsigned short* __restrict__ Bt,
    const float* __restrict__ b0, float* __restrict__ df) {
  __shared__ unsigned short As[128][64];
  __shared__ unsigned short Bs[64][64];
  const int tid = threadIdx.x;
  const int lane = tid & 63, wave = tid >> 6;
  const int h = lane >> 4, lr = lane & 15;
  const int wm = wave >> 1, wn = wave & 1;
  const int t0 = blockIdx.x * 128, n0 = blockIdx.y * 64;
  const int rs = lane >> 3;
  const int c8 = (lane & 7) ^ rs;

  const unsigned short* Ab = A + (size_t)t0 * DM + c8 * 8;
  const unsigned short* Bb = Bt + (size_t)n0 * DM + c8 * 8;

  f32x4 acc[4][2];
  const f32x4 zero4 = {0.f, 0.f, 0.f, 0.f};
#pragma unroll
  for (int i = 0; i < 4; i++)
#pragma unroll
    for (int j = 0; j < 2; j++) acc[i][j] = zero4;

  const int NT = DM / 64;
  for (int kt = 0; kt < NT; ++kt) {
    const int k0 = kt * 64;
#pragma unroll
    for (int i = 0; i < 4; ++i) {
      const int blk = wave * 4 + i;
      GLOAD16(Ab + (size_t)(blk * 8 + rs) * DM + k0, &As[blk * 8][0]);
    }
#pragma unroll
    for (int i = 0; i < 2; ++i) {
      const int blk = wave * 2 + i;
      GLOAD16(Bb + (size_t)(blk * 8 + rs) * DM + k0, &Bs[blk * 8][0]);
    }
    __syncthreads();
#pragma unroll
    for (int kk = 0; kk < 2; ++kk) {
      bf16x8 a[4], b[2];
      const int csw = ((kk * 4 + h) ^ (lr & 7)) * 8;
#pragma unroll
      for (int mi = 0; mi < 4; mi++) a[mi] = *(const bf16x8*)&As[wm * 64 + mi * 16 + lr][csw];
#pragma unroll
      for (int ni = 0; ni < 2; ni++) b[ni] = *(const bf16x8*)&Bs[wn * 32 + ni * 16 + lr][csw];
#pragma unroll
      for (int mi = 0; mi < 4; mi++)
#pragma unroll
        for (int ni = 0; ni < 2; ni++)
          acc[mi][ni] = __builtin_amdgcn_mfma_f32_16x16x32_bf16(a[mi], b[ni], acc[mi][ni], 0, 0, 0);
    }
    __syncthreads();
  }

#pragma unroll
  for (int mi = 0; mi < 4; mi++) {
#pragma unroll
    for (int j = 0; j < 4; j++) {
      int t = t0 + wm * 64 + mi * 16 + h * 4 + j;
      if (t >= T_LEN) continue;
#pragma unroll
      for (int ni = 0; ni < 2; ni++) {
        int n = n0 + wn * 32 + ni * 16 + lr;
        df[(size_t)t * DM + n] = acc[mi][ni][j] + b0[n];
      }
    }
  }
}

// ---------------- fused block-diagonal attention ----------------------------
__global__ __launch_bounds__(256) void attn_kernel(
    const unsigned short* __restrict__ Qb, const unsigned short* __restrict__ Kb,
    const unsigned short* __restrict__ Vtb, unsigned short* __restrict__ Ctx) {
  __shared__ unsigned short Ks[2][64][64];
  __shared__ unsigned short Vs[2][64][64];
  __shared__ unsigned short Ps[4][16][64];
  const int tid = threadIdx.x;
  const int lane = tid & 63, wave = tid >> 6;
  const int h = lane >> 4, lr = lane & 15;
  const int rs = lane >> 3;
  const int c8 = (lane & 7) ^ rs;
  int bid = blockIdx.x;
  const int qt = bid % 12; bid /= 12;
  const int ch = bid % N_CH; bid /= N_CH;
  const int hh = bid;

  const unsigned short* Qh = Qb + (size_t)hh * (T_PAD * 64);
  const unsigned short* Kh = Kb + (size_t)hh * (T_PAD * 64) + (size_t)(ch * CHUNK) * 64 + c8 * 8;
  const unsigned short* Vh = Vtb + (size_t)hh * (64 * T_PAD) + ch * CHUNK_PAD + c8 * 8;

  const int qrow0 = qt * 64 + wave * 16;
  const int tq = ch * CHUNK + qrow0 + lr;
  bf16x8 aq[2];
#pragma unroll
  for (int kk = 0; kk < 2; kk++)
    aq[kk] = *(const bf16x8*)(Qh + (size_t)tq * 64 + kk * 32 + h * 8);

  const f32x4 zero4 = {0.f, 0.f, 0.f, 0.f};
  f32x4 oacc[4];
#pragma unroll
  for (int i = 0; i < 4; i++) oacc[i] = zero4;
  float l_part[4] = {0.f, 0.f, 0.f, 0.f};

#define A_STAGE(buf, kt) do {                                                   \
    const int s0_ = (kt) * 64;                                                  \
    _Pragma("unroll")                                                           \
    for (int i_ = 0; i_ < 2; ++i_) {                                            \
      const int blk_ = wave * 2 + i_;                                           \
      const int r_ = blk_ * 8 + rs;                                             \
      GLOAD16(Kh + (size_t)(s0_ + r_) * 64, &Ks[buf][blk_ * 8][0]);             \
      GLOAD16(Vh + (size_t)r_ * T_PAD + s0_, &Vs[buf][blk_ * 8][0]);            \
    } } while (0)

  A_STAGE(0, 0);
  __syncthreads();
  int cur = 0;
  for (int kt = 0; kt < 12; ++kt) {
    if (kt + 1 < 12) A_STAGE(cur ^ 1, kt + 1);

    f32x4 sacc[4];
#pragma unroll
    for (int i = 0; i < 4; i++) sacc[i] = zero4;
#pragma unroll
    for (int kk = 0; kk < 2; kk++) {
      const int csw = ((kk * 4 + h) ^ (lr & 7)) * 8;
      bf16x8 bk[4];
#pragma unroll
      for (int ni = 0; ni < 4; ni++) bk[ni] = *(const bf16x8*)&Ks[cur][ni * 16 + lr][csw];
#pragma unroll
      for (int ni = 0; ni < 4; ni++)
        sacc[ni] = __builtin_amdgcn_mfma_f32_16x16x32_bf16(aq[kk], bk[ni], sacc[ni], 0, 0, 0);
    }

    const bool last = (kt == 11);
    float pexp[4][4];
#pragma unroll
    for (int ni = 0; ni < 4; ni++) {
#pragma unroll
      for (int j = 0; j < 4; j++) {
        float e = __expf(sacc[ni][j]);
        if (last && (ni * 16 + lr >= CHUNK - 704)) e = 0.f;
        pexp[ni][j] = e;
        l_part[j] += e;
      }
    }

#pragma unroll
    for (int ni = 0; ni < 4; ni++) {
#pragma unroll
      for (int j = 0; j < 4; j++) {
        int row = h * 4 + j;
        int col = ni * 16 + lr;
        Ps[wave][row][((col >> 3) ^ (row & 7)) * 8 + (col & 7)] = f2bf(pexp[ni][j]);
      }
    }

#pragma unroll
    for (int kk = 0; kk < 2; kk++) {
      const int csw = ((kk * 4 + h) ^ (lr & 7)) * 8;
      bf16x8 ap = *(const bf16x8*)&Ps[wave][lr][csw];
      bf16x8 bv[4];
#pragma unroll
      for (int nd = 0; nd < 4; nd++) bv[nd] = *(const bf16x8*)&Vs[cur][nd * 16 + lr][csw];
#pragma unroll
      for (int nd = 0; nd < 4; nd++)
        oacc[nd] = __builtin_amdgcn_mfma_f32_16x16x32_bf16(ap, bv[nd], oacc[nd], 0, 0, 0);
    }
    __syncthreads();
    cur ^= 1;
  }
#undef A_STAGE

#pragma unroll
  for (int j = 0; j < 4; j++) {
    float l = l_part[j];
#pragma unroll
    for (int off = 1; off < 16; off <<= 1) l += __shfl_xor(l, off, 64);
    int qr = qrow0 + h * 4 + j;
    if (qr >= CHUNK) continue;
    int t = ch * CHUNK + qr;
    float inv = 1.f / l;
#pragma unroll
    for (int nd = 0; nd < 4; nd++) {
      int d = nd * 16 + lr;
      Ctx[(size_t)t * DM + hh * 64 + d] = f2bf(oacc[nd][j] * inv);
    }
  }
}

extern "C" void kernel_launch(void* const* d_in, const int* in_sizes, int n_in,
                              void* d_out, int out_size, void* d_ws, size_t ws_size,
                              hipStream_t stream) {
  const float* hs = (const float*)d_in[0];
  const float* wq = (const float*)d_in[2];
  const float* bq = (const float*)d_in[3];
  const float* wk = (const float*)d_in[4];
  const float* bk = (const float*)d_in[5];
  const float* wv = (const float*)d_in[6];
  const float* bv = (const float*)d_in[7];
  const float* wo = (const float*)d_in[8];
  const float* bo = (const float*)d_in[9];

  char* ws = (char*)d_ws;
  unsigned short* Xb = (unsigned short*)ws;   ws += (size_t)T_PAD * DM * 2;
  unsigned short* Wcat = (unsigned short*)ws; ws += (size_t)4 * DM * DM * 2;
  unsigned short* Qb = (unsigned short*)ws;   ws += (size_t)NUM_HEADS * T_PAD * 64 * 2;
  unsigned short* Kb = (unsigned short*)ws;   ws += (size_t)NUM_HEADS * T_PAD * 64 * 2;
  unsigned short* Vtb = (unsigned short*)ws;  ws += (size_t)NUM_HEADS * 64 * T_PAD * 2;
  unsigned short* Ctx = (unsigned short*)ws;  ws += (size_t)T_PAD * DM * 2;

  cvt_bf16_kernel<<<T_PAD * DM / 4 / 256, 256, 0, stream>>>(hs, Xb);
  tr_bf16_kernel<<<dim3(40, 40, 4), dim3(32, 8), 0, stream>>>(wq, wk, wv, wo, Wcat);
  vpad_zero_kernel<<<(NUM_HEADS * 64 * N_CH * (CHUNK_PAD - CHUNK) + 255) / 256, 256, 0, stream>>>(Vtb);

  gemm256_kernel<<<dim3(12, 15), 512, 0, stream>>>(Xb, Wcat, bq, bk, bv, Qb, Kb, Vtb);

  attn_kernel<<<NUM_HEADS * N_CH * 12, 256, 0, stream>>>(Qb, Kb, Vtb, Ctx);

  gemm_out_kernel<<<dim3(24, 20), 256, 0, stream>>>(Ctx, Wcat + (size_t)3 * DM * DM, bo, (float*)d_out);
}

// Round 9
// 130.634 us; speedup vs baseline: 1.2170x; 1.2170x over previous
//
#include <hip/hip_runtime.h>

#define T_LEN 3000
#define DM 1280
#define NUM_HEADS 20
#define N_CH 4
#define CHUNK 750
#define CHUNK_PAD 768
#define T_PAD 3072

typedef __bf16 bf16x8 __attribute__((ext_vector_type(8)));
typedef float f32x4 __attribute__((ext_vector_type(4)));

typedef const __attribute__((address_space(1))) void* gas_p;
typedef __attribute__((address_space(3))) void* las_p;
#define GLOAD16(g, l) __builtin_amdgcn_global_load_lds((gas_p)(g), (las_p)(l), 16, 0, 0)

__device__ __forceinline__ unsigned short f2bf(float f) {
  union { float f; unsigned u; } x; x.f = f;
  unsigned r = x.u + 0x7FFFu + ((x.u >> 16) & 1u);
  return (unsigned short)(r >> 16);
}

// ---------------- fused prep: X cvt (+pad zero), 4x W transpose, V pad zero -
// 1D grid, 256 threads. Block ranges:
//   [0, NB_CVT): cvt hs fp32 -> Xb bf16 over [T_PAD][DM] (zero pad rows)
//   [NB_CVT, NB_CVT+NB_TR): transpose+cvt Wcat[z][n][k] = w[z][k][n]
//   last block: zero V chunk-pad columns
#define NB_CVT (T_PAD * DM / 4 / 256)        // 3840
#define NB_TR  (40 * 40 * 4)                 // 6400
__global__ __launch_bounds__(256) void prep_kernel(
    const float* __restrict__ hs, unsigned short* __restrict__ Xb,
    const float* __restrict__ w0, const float* __restrict__ w1,
    const float* __restrict__ w2, const float* __restrict__ w3,
    unsigned short* __restrict__ Wcat, unsigned short* __restrict__ Vtb) {
  const int b = blockIdx.x;
  if (b < NB_CVT) {
    int i = b * 256 + threadIdx.x;
    ushort4 o;
    if (i < T_LEN * DM / 4) {
      const float4 v = ((const float4*)hs)[i];
      o.x = f2bf(v.x); o.y = f2bf(v.y); o.z = f2bf(v.z); o.w = f2bf(v.w);
    } else {
      o.x = 0; o.y = 0; o.z = 0; o.w = 0;
    }
    ((ushort4*)Xb)[i] = o;
    return;
  }
  if (b < NB_CVT + NB_TR) {
    const int bb = b - NB_CVT;
    const int z = bb / 1600;
    const int rem = bb - z * 1600;
    const int bx = rem % 40, by = rem / 40;
    const float* in = z == 0 ? w0 : (z == 1 ? w1 : (z == 2 ? w2 : w3));
    unsigned short* o = Wcat + (size_t)z * DM * DM;
    __shared__ float tile[32][33];
    const int x = threadIdx.x & 31, y0 = threadIdx.x >> 5;  // 32 x 8
    const int n0 = bx * 32, k0 = by * 32;
    for (int y = y0; y < 32; y += 8) tile[y][x] = in[(k0 + y) * DM + n0 + x];
    __syncthreads();
    for (int y = y0; y < 32; y += 8) o[(n0 + y) * DM + k0 + x] = f2bf(tile[x][y]);
    return;
  }
  // V chunk-pad zero: H*64 rows x N_CH chunks x 18 pad cols = 92160 elems
  for (int i = threadIdx.x; i < NUM_HEADS * 64 * N_CH * (CHUNK_PAD - CHUNK); i += 256) {
    int c = i % (CHUNK_PAD - CHUNK); int r = i / (CHUNK_PAD - CHUNK);
    int ch = r % N_CH; int row = r / N_CH;
    Vtb[(size_t)row * T_PAD + ch * CHUNK_PAD + CHUNK + c] = 0;
  }
}

// ---------------- fused QKV GEMM (R3-exact m97 structure) -------------------
// 128^2 tile, single 32 KiB LDS pair, stage -> barrier -> compute -> barrier.
// grid (24, 30); sec = by/10: 0->Q (scaled 1/8), 1->K, 2->V^T
__global__ __launch_bounds__(256) void gemm_qkv_kernel(
    const unsigned short* __restrict__ A, const unsigned short* __restrict__ Bt,
    const float* __restrict__ b0, const float* __restrict__ b1, const float* __restrict__ b2,
    unsigned short* __restrict__ dq, unsigned short* __restrict__ dk,
    unsigned short* __restrict__ dv) {
  __shared__ unsigned short As[128][64];
  __shared__ unsigned short Bs[128][64];
  const int tid = threadIdx.x;
  const int lane = tid & 63, wave = tid >> 6;
  const int h = lane >> 4, lr = lane & 15;
  const int wm = wave >> 1, wn = wave & 1;
  const int t0 = blockIdx.x * 128, n0 = blockIdx.y * 128;
  const int rs = lane >> 3;              // sub-row within an 8-row block
  const int c8 = (lane & 7) ^ rs;        // inverse-swizzled source chunk

  const unsigned short* Ab = A + (size_t)t0 * DM + c8 * 8;
  const unsigned short* Bb = Bt + (size_t)n0 * DM + c8 * 8;

  f32x4 acc[4][4];
  const f32x4 zero4 = {0.f, 0.f, 0.f, 0.f};
#pragma unroll
  for (int i = 0; i < 4; i++)
#pragma unroll
    for (int j = 0; j < 4; j++) acc[i][j] = zero4;

  const int NT = DM / 64;  // 20
  for (int kt = 0; kt < NT; ++kt) {
    const int k0 = kt * 64;
#pragma unroll
    for (int i = 0; i < 4; ++i) {
      const int blk = wave * 4 + i;
      const size_t ro = (size_t)(blk * 8 + rs) * DM + k0;
      GLOAD16(Ab + ro, &As[blk * 8][0]);
      GLOAD16(Bb + ro, &Bs[blk * 8][0]);
    }
    __syncthreads();
#pragma unroll
    for (int kk = 0; kk < 2; ++kk) {
      bf16x8 a[4], b[4];
      const int csw = ((kk * 4 + h) ^ (lr & 7)) * 8;
#pragma unroll
      for (int mi = 0; mi < 4; mi++) a[mi] = *(const bf16x8*)&As[wm * 64 + mi * 16 + lr][csw];
#pragma unroll
      for (int ni = 0; ni < 4; ni++) b[ni] = *(const bf16x8*)&Bs[wn * 64 + ni * 16 + lr][csw];
#pragma unroll
      for (int mi = 0; mi < 4; mi++)
#pragma unroll
        for (int ni = 0; ni < 4; ni++)
          acc[mi][ni] = __builtin_amdgcn_mfma_f32_16x16x32_bf16(a[mi], b[ni], acc[mi][ni], 0, 0, 0);
    }
    __syncthreads();
  }

  const int sec = (int)blockIdx.y / 10;
  const float* bias = sec == 0 ? b0 : (sec == 1 ? b1 : b2);
  const float qs = sec == 0 ? 0.125f : 1.0f;
#pragma unroll
  for (int mi = 0; mi < 4; mi++) {
#pragma unroll
    for (int j = 0; j < 4; j++) {
      int t = t0 + wm * 64 + mi * 16 + h * 4 + j;
      if (t >= T_LEN) continue;
#pragma unroll
      for (int ni = 0; ni < 4; ni++) {
        int n = n0 + wn * 64 + ni * 16 + lr;
        int nn = n - sec * DM;
        float v = (acc[mi][ni][j] + bias[nn]) * qs;
        if (sec < 2) {
          unsigned short* dst = sec == 0 ? dq : dk;
          dst[(size_t)(nn >> 6) * (T_PAD * 64) + (size_t)t * 64 + (nn & 63)] = f2bf(v);
        } else {
          int ch = t / CHUNK, s = t - ch * CHUNK;
          dv[(size_t)(nn >> 6) * (64 * T_PAD) + (size_t)(nn & 63) * T_PAD + ch * CHUNK_PAD + s] = f2bf(v);
        }
      }
    }
  }
}

// ---------------- out-proj GEMM: 128x64 m97 structure -----------------------
__global__ __launch_bounds__(256) void gemm_out_kernel(
    const unsigned short* __restrict__ A, const unsigned short* __restrict__ Bt,
    const float* __restrict__ b0, float* __restrict__ df) {
  __shared__ unsigned short As[128][64];
  __shared__ unsigned short Bs[64][64];
  const int tid = threadIdx.x;
  const int lane = tid & 63, wave = tid >> 6;
  const int h = lane >> 4, lr = lane & 15;
  const int wm = wave >> 1, wn = wave & 1;
  const int t0 = blockIdx.x * 128, n0 = blockIdx.y * 64;
  const int rs = lane >> 3;
  const int c8 = (lane & 7) ^ rs;

  const unsigned short* Ab = A + (size_t)t0 * DM + c8 * 8;
  const unsigned short* Bb = Bt + (size_t)n0 * DM + c8 * 8;

  f32x4 acc[4][2];
  const f32x4 zero4 = {0.f, 0.f, 0.f, 0.f};
#pragma unroll
  for (int i = 0; i < 4; i++)
#pragma unroll
    for (int j = 0; j < 2; j++) acc[i][j] = zero4;

  const int NT = DM / 64;
  for (int kt = 0; kt < NT; ++kt) {
    const int k0 = kt * 64;
#pragma unroll
    for (int i = 0; i < 4; ++i) {
      const int blk = wave * 4 + i;
      GLOAD16(Ab + (size_t)(blk * 8 + rs) * DM + k0, &As[blk * 8][0]);
    }
#pragma unroll
    for (int i = 0; i < 2; ++i) {
      const int blk = wave * 2 + i;
      GLOAD16(Bb + (size_t)(blk * 8 + rs) * DM + k0, &Bs[blk * 8][0]);
    }
    __syncthreads();
#pragma unroll
    for (int kk = 0; kk < 2; ++kk) {
      bf16x8 a[4], b[2];
      const int csw = ((kk * 4 + h) ^ (lr & 7)) * 8;
#pragma unroll
      for (int mi = 0; mi < 4; mi++) a[mi] = *(const bf16x8*)&As[wm * 64 + mi * 16 + lr][csw];
#pragma unroll
      for (int ni = 0; ni < 2; ni++) b[ni] = *(const bf16x8*)&Bs[wn * 32 + ni * 16 + lr][csw];
#pragma unroll
      for (int mi = 0; mi < 4; mi++)
#pragma unroll
        for (int ni = 0; ni < 2; ni++)
          acc[mi][ni] = __builtin_amdgcn_mfma_f32_16x16x32_bf16(a[mi], b[ni], acc[mi][ni], 0, 0, 0);
    }
    __syncthreads();
  }

#pragma unroll
  for (int mi = 0; mi < 4; mi++) {
#pragma unroll
    for (int j = 0; j < 4; j++) {
      int t = t0 + wm * 64 + mi * 16 + h * 4 + j;
      if (t >= T_LEN) continue;
#pragma unroll
      for (int ni = 0; ni < 2; ni++) {
        int n = n0 + wn * 32 + ni * 16 + lr;
        df[(size_t)t * DM + n] = acc[mi][ni][j] + b0[n];
      }
    }
  }
}

// ---------------- fused block-diagonal attention ----------------------------
__global__ __launch_bounds__(256) void attn_kernel(
    const unsigned short* __restrict__ Qb, const unsigned short* __restrict__ Kb,
    const unsigned short* __restrict__ Vtb, unsigned short* __restrict__ Ctx) {
  __shared__ unsigned short Ks[2][64][64];
  __shared__ unsigned short Vs[2][64][64];
  __shared__ unsigned short Ps[4][16][64];
  const int tid = threadIdx.x;
  const int lane = tid & 63, wave = tid >> 6;
  const int h = lane >> 4, lr = lane & 15;
  const int rs = lane >> 3;
  const int c8 = (lane & 7) ^ rs;
  int bid = blockIdx.x;
  const int qt = bid % 12; bid /= 12;
  const int ch = bid % N_CH; bid /= N_CH;
  const int hh = bid;

  const unsigned short* Qh = Qb + (size_t)hh * (T_PAD * 64);
  const unsigned short* Kh = Kb + (size_t)hh * (T_PAD * 64) + (size_t)(ch * CHUNK) * 64 + c8 * 8;
  const unsigned short* Vh = Vtb + (size_t)hh * (64 * T_PAD) + ch * CHUNK_PAD + c8 * 8;

  const int qrow0 = qt * 64 + wave * 16;
  const int tq = ch * CHUNK + qrow0 + lr;
  bf16x8 aq[2];
#pragma unroll
  for (int kk = 0; kk < 2; kk++)
    aq[kk] = *(const bf16x8*)(Qh + (size_t)tq * 64 + kk * 32 + h * 8);

  const f32x4 zero4 = {0.f, 0.f, 0.f, 0.f};
  f32x4 oacc[4];
#pragma unroll
  for (int i = 0; i < 4; i++) oacc[i] = zero4;
  float l_part[4] = {0.f, 0.f, 0.f, 0.f};

#define A_STAGE(buf, kt) do {                                                   \
    const int s0_ = (kt) * 64;                                                  \
    _Pragma("unroll")                                                           \
    for (int i_ = 0; i_ < 2; ++i_) {                                            \
      const int blk_ = wave * 2 + i_;                                           \
      const int r_ = blk_ * 8 + rs;                                             \
      GLOAD16(Kh + (size_t)(s0_ + r_) * 64, &Ks[buf][blk_ * 8][0]);             \
      GLOAD16(Vh + (size_t)r_ * T_PAD + s0_, &Vs[buf][blk_ * 8][0]);            \
    } } while (0)

  A_STAGE(0, 0);
  __syncthreads();
  int cur = 0;
  for (int kt = 0; kt < 12; ++kt) {
    if (kt + 1 < 12) A_STAGE(cur ^ 1, kt + 1);

    f32x4 sacc[4];
#pragma unroll
    for (int i = 0; i < 4; i++) sacc[i] = zero4;
#pragma unroll
    for (int kk = 0; kk < 2; kk++) {
      const int csw = ((kk * 4 + h) ^ (lr & 7)) * 8;
      bf16x8 bk[4];
#pragma unroll
      for (int ni = 0; ni < 4; ni++) bk[ni] = *(const bf16x8*)&Ks[cur][ni * 16 + lr][csw];
#pragma unroll
      for (int ni = 0; ni < 4; ni++)
        sacc[ni] = __builtin_amdgcn_mfma_f32_16x16x32_bf16(aq[kk], bk[ni], sacc[ni], 0, 0, 0);
    }

    const bool last = (kt == 11);
    float pexp[4][4];
#pragma unroll
    for (int ni = 0; ni < 4; ni++) {
#pragma unroll
      for (int j = 0; j < 4; j++) {
        float e = __expf(sacc[ni][j]);
        if (last && (ni * 16 + lr >= CHUNK - 704)) e = 0.f;
        pexp[ni][j] = e;
        l_part[j] += e;
      }
    }

#pragma unroll
    for (int ni = 0; ni < 4; ni++) {
#pragma unroll
      for (int j = 0; j < 4; j++) {
        int row = h * 4 + j;
        int col = ni * 16 + lr;
        Ps[wave][row][((col >> 3) ^ (row & 7)) * 8 + (col & 7)] = f2bf(pexp[ni][j]);
      }
    }

#pragma unroll
    for (int kk = 0; kk < 2; kk++) {
      const int csw = ((kk * 4 + h) ^ (lr & 7)) * 8;
      bf16x8 ap = *(const bf16x8*)&Ps[wave][lr][csw];
      bf16x8 bv[4];
#pragma unroll
      for (int nd = 0; nd < 4; nd++) bv[nd] = *(const bf16x8*)&Vs[cur][nd * 16 + lr][csw];
#pragma unroll
      for (int nd = 0; nd < 4; nd++)
        oacc[nd] = __builtin_amdgcn_mfma_f32_16x16x32_bf16(ap, bv[nd], oacc[nd], 0, 0, 0);
    }
    __syncthreads();
    cur ^= 1;
  }
#undef A_STAGE

#pragma unroll
  for (int j = 0; j < 4; j++) {
    float l = l_part[j];
#pragma unroll
    for (int off = 1; off < 16; off <<= 1) l += __shfl_xor(l, off, 64);
    int qr = qrow0 + h * 4 + j;
    if (qr >= CHUNK) continue;
    int t = ch * CHUNK + qr;
    float inv = 1.f / l;
#pragma unroll
    for (int nd = 0; nd < 4; nd++) {
      int d = nd * 16 + lr;
      Ctx[(size_t)t * DM + hh * 64 + d] = f2bf(oacc[nd][j] * inv);
    }
  }
}

extern "C" void kernel_launch(void* const* d_in, const int* in_sizes, int n_in,
                              void* d_out, int out_size, void* d_ws, size_t ws_size,
                              hipStream_t stream) {
  const float* hs = (const float*)d_in[0];
  const float* wq = (const float*)d_in[2];
  const float* bq = (const float*)d_in[3];
  const float* wk = (const float*)d_in[4];
  const float* bk = (const float*)d_in[5];
  const float* wv = (const float*)d_in[6];
  const float* bv = (const float*)d_in[7];
  const float* wo = (const float*)d_in[8];
  const float* bo = (const float*)d_in[9];

  char* ws = (char*)d_ws;
  unsigned short* Xb = (unsigned short*)ws;   ws += (size_t)T_PAD * DM * 2;
  unsigned short* Wcat = (unsigned short*)ws; ws += (size_t)4 * DM * DM * 2;
  unsigned short* Qb = (unsigned short*)ws;   ws += (size_t)NUM_HEADS * T_PAD * 64 * 2;
  unsigned short* Kb = (unsigned short*)ws;   ws += (size_t)NUM_HEADS * T_PAD * 64 * 2;
  unsigned short* Vtb = (unsigned short*)ws;  ws += (size_t)NUM_HEADS * 64 * T_PAD * 2;
  unsigned short* Ctx = (unsigned short*)ws;  ws += (size_t)T_PAD * DM * 2;

  prep_kernel<<<NB_CVT + NB_TR + 1, 256, 0, stream>>>(hs, Xb, wq, wk, wv, wo, Wcat, Vtb);

  gemm_qkv_kernel<<<dim3(24, 30), 256, 0, stream>>>(Xb, Wcat, bq, bk, bv, Qb, Kb, Vtb);

  attn_kernel<<<NUM_HEADS * N_CH * 12, 256, 0, stream>>>(Qb, Kb, Vtb, Ctx);

  gemm_out_kernel<<<dim3(24, 20), 256, 0, stream>>>(Ctx, Wcat + (size_t)3 * DM * DM, bo, (float*)d_out);
}

// Round 10
// 130.149 us; speedup vs baseline: 1.2215x; 1.0037x over previous
//
#include <hip/hip_runtime.h>

#define T_LEN 3000
#define DM 1280
#define NUM_HEADS 20
#define N_CH 4
#define CHUNK 750
#define CHUNK_PAD 768
#define T_PAD 3072

typedef __bf16 bf16x8 __attribute__((ext_vector_type(8)));
typedef float f32x4 __attribute__((ext_vector_type(4)));
typedef float f32x16 __attribute__((ext_vector_type(16)));

typedef const __attribute__((address_space(1))) void* gas_p;
typedef __attribute__((address_space(3))) void* las_p;
#define GLOAD16(g, l) __builtin_amdgcn_global_load_lds((gas_p)(g), (las_p)(l), 16, 0, 0)

__device__ __forceinline__ unsigned short f2bf(float f) {
  union { float f; unsigned u; } x; x.f = f;
  unsigned r = x.u + 0x7FFFu + ((x.u >> 16) & 1u);
  return (unsigned short)(r >> 16);
}

// ---------------- fused prep: X cvt (+pad zero), 4x W transpose, V pad zero -
#define NB_CVT (T_PAD * DM / 4 / 256)        // 3840
#define NB_TR  (40 * 40 * 4)                 // 6400
__global__ __launch_bounds__(256) void prep_kernel(
    const float* __restrict__ hs, unsigned short* __restrict__ Xb,
    const float* __restrict__ w0, const float* __restrict__ w1,
    const float* __restrict__ w2, const float* __restrict__ w3,
    unsigned short* __restrict__ Wcat, unsigned short* __restrict__ Vtb) {
  const int b = blockIdx.x;
  if (b < NB_CVT) {
    int i = b * 256 + threadIdx.x;
    ushort4 o;
    if (i < T_LEN * DM / 4) {
      const float4 v = ((const float4*)hs)[i];
      o.x = f2bf(v.x); o.y = f2bf(v.y); o.z = f2bf(v.z); o.w = f2bf(v.w);
    } else {
      o.x = 0; o.y = 0; o.z = 0; o.w = 0;
    }
    ((ushort4*)Xb)[i] = o;
    return;
  }
  if (b < NB_CVT + NB_TR) {
    const int bb = b - NB_CVT;
    const int z = bb / 1600;
    const int rem = bb - z * 1600;
    const int bx = rem % 40, by = rem / 40;
    const float* in = z == 0 ? w0 : (z == 1 ? w1 : (z == 2 ? w2 : w3));
    unsigned short* o = Wcat + (size_t)z * DM * DM;
    __shared__ float tile[32][33];
    const int x = threadIdx.x & 31, y0 = threadIdx.x >> 5;  // 32 x 8
    const int n0 = bx * 32, k0 = by * 32;
    for (int y = y0; y < 32; y += 8) tile[y][x] = in[(k0 + y) * DM + n0 + x];
    __syncthreads();
    for (int y = y0; y < 32; y += 8) o[(n0 + y) * DM + k0 + x] = f2bf(tile[x][y]);
    return;
  }
  for (int i = threadIdx.x; i < NUM_HEADS * 64 * N_CH * (CHUNK_PAD - CHUNK); i += 256) {
    int c = i % (CHUNK_PAD - CHUNK); int r = i / (CHUNK_PAD - CHUNK);
    int ch = r % N_CH; int row = r / N_CH;
    Vtb[(size_t)row * T_PAD + ch * CHUNK_PAD + CHUNK + c] = 0;
  }
}

// ---------------- fused QKV GEMM (R3-exact m97 structure) -------------------
__global__ __launch_bounds__(256) void gemm_qkv_kernel(
    const unsigned short* __restrict__ A, const unsigned short* __restrict__ Bt,
    const float* __restrict__ b0, const float* __restrict__ b1, const float* __restrict__ b2,
    unsigned short* __restrict__ dq, unsigned short* __restrict__ dk,
    unsigned short* __restrict__ dv) {
  __shared__ unsigned short As[128][64];
  __shared__ unsigned short Bs[128][64];
  const int tid = threadIdx.x;
  const int lane = tid & 63, wave = tid >> 6;
  const int h = lane >> 4, lr = lane & 15;
  const int wm = wave >> 1, wn = wave & 1;
  const int t0 = blockIdx.x * 128, n0 = blockIdx.y * 128;
  const int rs = lane >> 3;
  const int c8 = (lane & 7) ^ rs;

  const unsigned short* Ab = A + (size_t)t0 * DM + c8 * 8;
  const unsigned short* Bb = Bt + (size_t)n0 * DM + c8 * 8;

  f32x4 acc[4][4];
  const f32x4 zero4 = {0.f, 0.f, 0.f, 0.f};
#pragma unroll
  for (int i = 0; i < 4; i++)
#pragma unroll
    for (int j = 0; j < 4; j++) acc[i][j] = zero4;

  const int NT = DM / 64;  // 20
  for (int kt = 0; kt < NT; ++kt) {
    const int k0 = kt * 64;
#pragma unroll
    for (int i = 0; i < 4; ++i) {
      const int blk = wave * 4 + i;
      const size_t ro = (size_t)(blk * 8 + rs) * DM + k0;
      GLOAD16(Ab + ro, &As[blk * 8][0]);
      GLOAD16(Bb + ro, &Bs[blk * 8][0]);
    }
    __syncthreads();
#pragma unroll
    for (int kk = 0; kk < 2; ++kk) {
      bf16x8 a[4], b[4];
      const int csw = ((kk * 4 + h) ^ (lr & 7)) * 8;
#pragma unroll
      for (int mi = 0; mi < 4; mi++) a[mi] = *(const bf16x8*)&As[wm * 64 + mi * 16 + lr][csw];
#pragma unroll
      for (int ni = 0; ni < 4; ni++) b[ni] = *(const bf16x8*)&Bs[wn * 64 + ni * 16 + lr][csw];
#pragma unroll
      for (int mi = 0; mi < 4; mi++)
#pragma unroll
        for (int ni = 0; ni < 4; ni++)
          acc[mi][ni] = __builtin_amdgcn_mfma_f32_16x16x32_bf16(a[mi], b[ni], acc[mi][ni], 0, 0, 0);
    }
    __syncthreads();
  }

  const int sec = (int)blockIdx.y / 10;
  const float* bias = sec == 0 ? b0 : (sec == 1 ? b1 : b2);
  const float qs = sec == 0 ? 0.125f : 1.0f;
#pragma unroll
  for (int mi = 0; mi < 4; mi++) {
#pragma unroll
    for (int j = 0; j < 4; j++) {
      int t = t0 + wm * 64 + mi * 16 + h * 4 + j;
      if (t >= T_LEN) continue;
#pragma unroll
      for (int ni = 0; ni < 4; ni++) {
        int n = n0 + wn * 64 + ni * 16 + lr;
        int nn = n - sec * DM;
        float v = (acc[mi][ni][j] + bias[nn]) * qs;
        if (sec < 2) {
          unsigned short* dst = sec == 0 ? dq : dk;
          dst[(size_t)(nn >> 6) * (T_PAD * 64) + (size_t)t * 64 + (nn & 63)] = f2bf(v);
        } else {
          int ch = t / CHUNK, s = t - ch * CHUNK;
          dv[(size_t)(nn >> 6) * (64 * T_PAD) + (size_t)(nn & 63) * T_PAD + ch * CHUNK_PAD + s] = f2bf(v);
        }
      }
    }
  }
}

// ---------------- out-proj GEMM: 128x64 m97 structure -----------------------
__global__ __launch_bounds__(256) void gemm_out_kernel(
    const unsigned short* __restrict__ A, const unsigned short* __restrict__ Bt,
    const float* __restrict__ b0, float* __restrict__ df) {
  __shared__ unsigned short As[128][64];
  __shared__ unsigned short Bs[64][64];
  const int tid = threadIdx.x;
  const int lane = tid & 63, wave = tid >> 6;
  const int h = lane >> 4, lr = lane & 15;
  const int wm = wave >> 1, wn = wave & 1;
  const int t0 = blockIdx.x * 128, n0 = blockIdx.y * 64;
  const int rs = lane >> 3;
  const int c8 = (lane & 7) ^ rs;

  const unsigned short* Ab = A + (size_t)t0 * DM + c8 * 8;
  const unsigned short* Bb = Bt + (size_t)n0 * DM + c8 * 8;

  f32x4 acc[4][2];
  const f32x4 zero4 = {0.f, 0.f, 0.f, 0.f};
#pragma unroll
  for (int i = 0; i < 4; i++)
#pragma unroll
    for (int j = 0; j < 2; j++) acc[i][j] = zero4;

  const int NT = DM / 64;
  for (int kt = 0; kt < NT; ++kt) {
    const int k0 = kt * 64;
#pragma unroll
    for (int i = 0; i < 4; ++i) {
      const int blk = wave * 4 + i;
      GLOAD16(Ab + (size_t)(blk * 8 + rs) * DM + k0, &As[blk * 8][0]);
    }
#pragma unroll
    for (int i = 0; i < 2; ++i) {
      const int blk = wave * 2 + i;
      GLOAD16(Bb + (size_t)(blk * 8 + rs) * DM + k0, &Bs[blk * 8][0]);
    }
    __syncthreads();
#pragma unroll
    for (int kk = 0; kk < 2; ++kk) {
      bf16x8 a[4], b[2];
      const int csw = ((kk * 4 + h) ^ (lr & 7)) * 8;
#pragma unroll
      for (int mi = 0; mi < 4; mi++) a[mi] = *(const bf16x8*)&As[wm * 64 + mi * 16 + lr][csw];
#pragma unroll
      for (int ni = 0; ni < 2; ni++) b[ni] = *(const bf16x8*)&Bs[wn * 32 + ni * 16 + lr][csw];
#pragma unroll
      for (int mi = 0; mi < 4; mi++)
#pragma unroll
        for (int ni = 0; ni < 2; ni++)
          acc[mi][ni] = __builtin_amdgcn_mfma_f32_16x16x32_bf16(a[mi], b[ni], acc[mi][ni], 0, 0, 0);
    }
    __syncthreads();
  }

#pragma unroll
  for (int mi = 0; mi < 4; mi++) {
#pragma unroll
    for (int j = 0; j < 4; j++) {
      int t = t0 + wm * 64 + mi * 16 + h * 4 + j;
      if (t >= T_LEN) continue;
#pragma unroll
      for (int ni = 0; ni < 2; ni++) {
        int n = n0 + wn * 32 + ni * 16 + lr;
        df[(size_t)t * DM + n] = acc[mi][ni][j] + b0[n];
      }
    }
  }
}

// ---------------- fused block-diagonal attention (32x32 MFMA) ---------------
// grid = H * N_CH * 6; 256 thr = 4 waves x 32 q-rows (128 q-rows/block).
// No-max softmax; Q pre-scaled 1/8. Per KV-64 tile per wave:
//   QK^T: 8 mfma_32x32x16 (A=Q in reg, B=K from LDS)
//   PV  : 8 mfma_32x32x16 (A=P via swizzled Ps LDS, B=V^T from LDS)
// C/D layout: col=lane&31, row=(reg&3)+8*(reg>>2)+4*(lane>>5).
// A/B frag: col(or row)=lane&31, k = (lane>>5)*8 + elem.
__global__ __launch_bounds__(256) void attn_kernel(
    const unsigned short* __restrict__ Qb, const unsigned short* __restrict__ Kb,
    const unsigned short* __restrict__ Vtb, unsigned short* __restrict__ Ctx) {
  __shared__ unsigned short Ks[2][64][64];
  __shared__ unsigned short Vs[2][64][64];
  __shared__ unsigned short Ps[4][32][64];
  const int tid = threadIdx.x;
  const int lane = tid & 63, wave = tid >> 6;
  const int l31 = lane & 31, hi = lane >> 5;
  const int rs = lane >> 3;
  const int c8s = (lane & 7) ^ rs;          // inverse-swizzled staging chunk
  int bid = blockIdx.x;
  const int qt = bid % 6; bid /= 6;
  const int ch = bid % N_CH; bid /= N_CH;
  const int hh = bid;

  const unsigned short* Qh = Qb + (size_t)hh * (T_PAD * 64);
  const unsigned short* Kh = Kb + (size_t)hh * (T_PAD * 64) + (size_t)(ch * CHUNK) * 64 + c8s * 8;
  const unsigned short* Vh = Vtb + (size_t)hh * (64 * T_PAD) + ch * CHUNK_PAD + c8s * 8;

  const int qrow0 = qt * 128 + wave * 32;
  const int tq = ch * CHUNK + qrow0 + l31;   // <= 3017 < T_PAD
  bf16x8 aq[4];
#pragma unroll
  for (int s = 0; s < 4; s++)
    aq[s] = *(const bf16x8*)(Qh + (size_t)tq * 64 + s * 16 + hi * 8);

  f32x16 oacc0, oacc1;
#pragma unroll
  for (int i = 0; i < 16; i++) { oacc0[i] = 0.f; oacc1[i] = 0.f; }
  float l_part[16];
#pragma unroll
  for (int i = 0; i < 16; i++) l_part[i] = 0.f;

#define A_STAGE(buf, kt) do {                                                   \
    const int s0_ = (kt) * 64;                                                  \
    _Pragma("unroll")                                                           \
    for (int i_ = 0; i_ < 2; ++i_) {                                            \
      const int blk_ = wave * 2 + i_;                                           \
      const int r_ = blk_ * 8 + rs;                                             \
      GLOAD16(Kh + (size_t)(s0_ + r_) * 64, &Ks[buf][blk_ * 8][0]);             \
      GLOAD16(Vh + (size_t)r_ * T_PAD + s0_, &Vs[buf][blk_ * 8][0]);            \
    } } while (0)

  A_STAGE(0, 0);
  __syncthreads();
  int cur = 0;
  const int xk = l31 & 7;                    // row-XOR key for LDS reads
  for (int kt = 0; kt < 12; ++kt) {
    if (kt + 1 < 12) A_STAGE(cur ^ 1, kt + 1);

    // S = Q @ K^T  (two 32-col kv subtiles)
    f32x16 s0, s1;
#pragma unroll
    for (int i = 0; i < 16; i++) { s0[i] = 0.f; s1[i] = 0.f; }
    __builtin_amdgcn_s_setprio(1);
#pragma unroll
    for (int s = 0; s < 4; s++) {
      const int cx = ((2 * s + hi) ^ xk) * 8;
      bf16x8 k0 = *(const bf16x8*)&Ks[cur][l31][cx];
      bf16x8 k1 = *(const bf16x8*)&Ks[cur][32 + l31][cx];
      s0 = __builtin_amdgcn_mfma_f32_32x32x16_bf16(aq[s], k0, s0, 0, 0, 0);
      s1 = __builtin_amdgcn_mfma_f32_32x32x16_bf16(aq[s], k1, s1, 0, 0, 0);
    }
    __builtin_amdgcn_s_setprio(0);

    // P = exp(S); accumulate row-sum; write P to per-wave swizzled Ps
    const bool lastt = (kt == 11);
#pragma unroll
    for (int r = 0; r < 16; r++) {
      float e0 = __expf(s0[r]);
      float e1 = __expf(s1[r]);
      if (lastt && (l31 >= 14)) e1 = 0.f;    // cols 736+l31 >= 750
      l_part[r] += e0 + e1;
      const int row = (r & 3) + 8 * (r >> 2) + 4 * hi;
      const int r7 = (r & 3) + 4 * hi;       // row & 7
      Ps[wave][row][(((l31 >> 3) ^ r7) << 3) + (l31 & 7)] = f2bf(e0);
      Ps[wave][row][((((l31 >> 3) + 4) ^ r7) << 3) + (l31 & 7)] = f2bf(e1);
    }

    // O += P @ V  (two 32-col d subtiles)
    __builtin_amdgcn_s_setprio(1);
#pragma unroll
    for (int s = 0; s < 4; s++) {
      const int cx = ((2 * s + hi) ^ xk) * 8;
      bf16x8 pa = *(const bf16x8*)&Ps[wave][l31][cx];
      bf16x8 v0 = *(const bf16x8*)&Vs[cur][l31][cx];
      bf16x8 v1 = *(const bf16x8*)&Vs[cur][32 + l31][cx];
      oacc0 = __builtin_amdgcn_mfma_f32_32x32x16_bf16(pa, v0, oacc0, 0, 0, 0);
      oacc1 = __builtin_amdgcn_mfma_f32_32x32x16_bf16(pa, v1, oacc1, 0, 0, 0);
    }
    __builtin_amdgcn_s_setprio(0);
    __syncthreads();
    cur ^= 1;
  }
#undef A_STAGE

  // deferred row-sum reduce (once) + write
#pragma unroll
  for (int r = 0; r < 16; r++) {
    float l = l_part[r];
#pragma unroll
    for (int off = 1; off < 32; off <<= 1) l += __shfl_xor(l, off, 64);
    l_part[r] = 1.f / l;
  }
#pragma unroll
  for (int r = 0; r < 16; r++) {
    const int row = (r & 3) + 8 * (r >> 2) + 4 * hi;
    int qr = qrow0 + row;
    if (qr >= CHUNK) continue;
    int t = ch * CHUNK + qr;
    Ctx[(size_t)t * DM + hh * 64 + l31] = f2bf(oacc0[r] * l_part[r]);
    Ctx[(size_t)t * DM + hh * 64 + 32 + l31] = f2bf(oacc1[r] * l_part[r]);
  }
}

extern "C" void kernel_launch(void* const* d_in, const int* in_sizes, int n_in,
                              void* d_out, int out_size, void* d_ws, size_t ws_size,
                              hipStream_t stream) {
  const float* hs = (const float*)d_in[0];
  const float* wq = (const float*)d_in[2];
  const float* bq = (const float*)d_in[3];
  const float* wk = (const float*)d_in[4];
  const float* bk = (const float*)d_in[5];
  const float* wv = (const float*)d_in[6];
  const float* bv = (const float*)d_in[7];
  const float* wo = (const float*)d_in[8];
  const float* bo = (const float*)d_in[9];

  char* ws = (char*)d_ws;
  unsigned short* Xb = (unsigned short*)ws;   ws += (size_t)T_PAD * DM * 2;
  unsigned short* Wcat = (unsigned short*)ws; ws += (size_t)4 * DM * DM * 2;
  unsigned short* Qb = (unsigned short*)ws;   ws += (size_t)NUM_HEADS * T_PAD * 64 * 2;
  unsigned short* Kb = (unsigned short*)ws;   ws += (size_t)NUM_HEADS * T_PAD * 64 * 2;
  unsigned short* Vtb = (unsigned short*)ws;  ws += (size_t)NUM_HEADS * 64 * T_PAD * 2;
  unsigned short* Ctx = (unsigned short*)ws;  ws += (size_t)T_PAD * DM * 2;

  prep_kernel<<<NB_CVT + NB_TR + 1, 256, 0, stream>>>(hs, Xb, wq, wk, wv, wo, Wcat, Vtb);

  gemm_qkv_kernel<<<dim3(24, 30), 256, 0, stream>>>(Xb, Wcat, bq, bk, bv, Qb, Kb, Vtb);

  attn_kernel<<<NUM_HEADS * N_CH * 6, 256, 0, stream>>>(Qb, Kb, Vtb, Ctx);

  gemm_out_kernel<<<dim3(24, 20), 256, 0, stream>>>(Ctx, Wcat + (size_t)3 * DM * DM, bo, (float*)d_out);
}